// Round 2
// baseline (23372.273 us; speedup 1.0000x reference)
//
#include <hip/hip_runtime.h>

#define T_STEPS 65536
#define NIN 99
#define HID 64
#define G4 256   // 4*HID gates
#define TS 128   // timesteps per block in the projection kernel
#define PF 8     // prefetch depth (steps) in the recurrence kernel

typedef _Float16 half2v __attribute__((ext_vector_type(2)));

__device__ __forceinline__ float frcp(float x) { return __builtin_amdgcn_rcpf(x); }
__device__ __forceinline__ float fexp2(float x) { return __builtin_amdgcn_exp2f(x); }

#define LOG2E 1.4426950408889634f

__device__ __forceinline__ float sigmoid_f(float x) { return frcp(1.0f + fexp2(x * -LOG2E)); }
__device__ __forceinline__ float tanh_f(float x) {
    float ax = fabsf(x);
    float e  = fexp2(ax * (2.0f * LOG2E));     // inf for large ax fine: rcp(inf)=0
    float r  = 1.0f - 2.0f * frcp(e + 1.0f);
    return copysignf(r, x);
}

// pack two f32 into half2 (v_cvt_pkrtz_f16_f32, 1 instr); bit-cast from the
// builtin's __fp16-vector return type to the _Float16-vector fdot2 wants.
__device__ __forceinline__ half2v pk16(float a, float b) {
#if __has_builtin(__builtin_amdgcn_cvt_pkrtz)
    return __builtin_bit_cast(half2v, __builtin_amdgcn_cvt_pkrtz(a, b));
#else
    half2v r; r.x = (_Float16)a; r.y = (_Float16)b; return r;
#endif
}
// v_dot2_f32_f16: 2 MACs per instr, f32 accumulate. Fallback keeps it compiling.
__device__ __forceinline__ float fdot2f(half2v a, half2v b, float c) {
#if __has_builtin(__builtin_amdgcn_fdot2)
    return __builtin_amdgcn_fdot2(a, b, c, false);
#else
    return fmaf((float)a.x, (float)b.x, fmaf((float)a.y, (float)b.y, c));
#endif
}

// LDS-only barrier: waits ds/smem (lgkmcnt) but leaves global loads (vmcnt)
// in flight across the barrier. __syncthreads() would drain vmcnt(0) and
// kill the xz prefetch every step (R6 post-mortem).
#define BAR_LGKM() asm volatile("s_waitcnt lgkmcnt(0)\n\ts_barrier" ::: "memory")

// ---------------- Kernel 1: xz2[t][unit][4] = gates (i,f,g,o) of unit ----------------
__global__ __launch_bounds__(256, 1) void xz_kernel(
    const float* __restrict__ x, const float* __restrict__ W_ih,
    const float* __restrict__ b_ih, const float* __restrict__ b_hh,
    float* __restrict__ xz2) {
    __shared__ __align__(16) float xs[TS * 100];   // padded rows: 400 B stride
    const int g  = threadIdx.x;                    // gate row 0..255
    const int t0 = blockIdx.x * TS;
    const int unit = g & 63, d = g >> 6;           // transposed write position

    for (int i = g; i < TS * NIN; i += 256) {
        int tl = i / NIN;
        int j  = i - tl * NIN;
        xs[tl * 100 + j] = x[(size_t)t0 * NIN + i];
    }

    float w[NIN];
#pragma unroll
    for (int j = 0; j < NIN; ++j) w[j] = W_ih[g * NIN + j];
    const float bias = b_ih[g] + b_hh[g];
    __syncthreads();

    for (int tl = 0; tl < TS; ++tl) {
        const float* xr = &xs[tl * 100];
        float a0 = bias, a1 = 0.f, a2 = 0.f, a3 = 0.f;
#pragma unroll
        for (int j4 = 0; j4 < 24; ++j4) {
            float4 xv = *(const float4*)(xr + 4 * j4);
            a0 = fmaf(w[4 * j4 + 0], xv.x, a0);
            a1 = fmaf(w[4 * j4 + 1], xv.y, a1);
            a2 = fmaf(w[4 * j4 + 2], xv.z, a2);
            a3 = fmaf(w[4 * j4 + 3], xv.w, a3);
        }
        a0 = fmaf(w[96], xr[96], a0);
        a1 = fmaf(w[97], xr[97], a1);
        a2 = fmaf(w[98], xr[98], a2);
        xz2[(size_t)(t0 + tl) * G4 + unit * 4 + d] = (a0 + a1) + (a2 + a3);
    }
}

// ---------------- Kernel 2: split-K LSTM, f16 dot2 matvec, lgkm-only barrier ----------------
// Phase 1: thread (wv,l) computes the 4 gates (i,f,g,o) OF UNIT l over k-chunk
//   [16wv,16wv+16): 1 mov_dpp + 1 cvt_pkrtz + 8 readlane (packed h pairs) +
//   32 v_dot2_f32_f16 (f32 accumulate); writes one float4 partial.
// BAR_LGKM (global prefetch stays in flight).
// Phase 2 (replicated): lane l reads the OTHER 3 chunks' float4 partials
//   (3 overlapping ds_read_b128), reduces with its own in-register partial,
//   activates, updates its own c,h. Every wave ends with identical h[l] in
//   lane l. xz supply rotates: wave (u&3) initializes with step u's xz
//   (balances prefetch loads across waves, no wave-0 barrier straggler).
__global__ __launch_bounds__(256, 1) __attribute__((amdgpu_waves_per_eu(1)))
void lstm_kernel(
    const float* __restrict__ xz2, const float* __restrict__ W_hh,
    const float* __restrict__ W1, const float* __restrict__ W2,
    const float* __restrict__ b2, float* __restrict__ out) {
    __shared__ __align__(16) float4 pbuf[2][4][HID];   // [parity][k-chunk][unit]
    __shared__ float hfin[HID];
    __shared__ float hbuf[32];
    const int tid = threadIdx.x;
    const int l   = tid & 63;
    const int wv  = tid >> 6;
    const int sb  = __builtin_amdgcn_readfirstlane(16 * wv);   // k-chunk base

    // W_hh rows l (i), 64+l (f), 128+l (g), 192+l (o); cols [sb, sb+16)
    // packed once into 8 half2 per gate (f32 -> f16 RTZ; |W|<=0.125 exact-ish)
    const float* Wb = W_hh + l * HID + sb;
    int wiP[8], wfP[8], wgP[8], woP[8];
#pragma unroll
    for (int j = 0; j < 8; ++j) {
        wiP[j] = __builtin_bit_cast(int, pk16(Wb[2 * j + 0],     Wb[2 * j + 1]));
        wfP[j] = __builtin_bit_cast(int, pk16(Wb[2 * j + 4096],  Wb[2 * j + 4097]));
        wgP[j] = __builtin_bit_cast(int, pk16(Wb[2 * j + 8192],  Wb[2 * j + 8193]));
        woP[j] = __builtin_bit_cast(int, pk16(Wb[2 * j + 12288], Wb[2 * j + 12289]));
        asm volatile("" : "+v"(wiP[j]), "+v"(wfP[j]), "+v"(wgP[j]), "+v"(woP[j]));
    }

    float h = 0.0f, c = 0.0f;       // lane l of every wave: h[l], c[l]

    // xz columns: unit l's 4 gates contiguous -> one dwordx4.
    // Rotation: wave w supplies steps u with (u&3)==w; holds 2 float4s per block.
    const float* zi = xz2 + 4 * l;
    float4 zc0 = *(const float4*)(zi + (size_t)(wv)     * G4);
    float4 zc1 = *(const float4*)(zi + (size_t)(wv + 4) * G4);
    float4 zn0 = make_float4(0.f, 0.f, 0.f, 0.f);
    float4 zn1 = make_float4(0.f, 0.f, 0.f, 0.f);

    for (int tb = 0; tb < T_STEPS; tb += PF) {
        if (tb + PF < T_STEPS) {
            zn0 = *(const float4*)(zi + (size_t)(tb + PF + wv)     * G4);
            zn1 = *(const float4*)(zi + (size_t)(tb + PF + wv + 4) * G4);
        }
#pragma unroll
        for (int u = 0; u < PF; ++u) {
            const int par = u & 1;
            // phase 1: 4 gates of unit l over k-chunk [sb, sb+16)
            float ai, af, ag, ao;
            if (wv == (u & 3)) {                      // wave-uniform branch
                float4 z = (u < 4) ? zc0 : zc1;       // compile-time select
                ai = z.x; af = z.y; ag = z.z; ao = z.w;
            } else { ai = 0.f; af = 0.f; ag = 0.f; ao = 0.f; }

            // pack (h[2j], h[2j+1]) in even lanes: lane-xor-1 neighbor via DPP
#if __has_builtin(__builtin_amdgcn_mov_dpp)
            float hn = __int_as_float(__builtin_amdgcn_mov_dpp(
                __float_as_int(h), 0xB1 /*quad_perm [1,0,3,2]*/, 0xF, 0xF, true));
#else
            float hn = __shfl_xor(h, 1, 64);
#endif
            const int hpi = __builtin_bit_cast(int, pk16(h, hn));
#pragma unroll
            for (int j = 0; j < 8; ++j) {
                half2v hpj = __builtin_bit_cast(half2v,
                    __builtin_amdgcn_readlane(hpi, sb + 2 * j));
                ai = fdot2f(__builtin_bit_cast(half2v, wiP[j]), hpj, ai);
                af = fdot2f(__builtin_bit_cast(half2v, wfP[j]), hpj, af);
                ag = fdot2f(__builtin_bit_cast(half2v, wgP[j]), hpj, ag);
                ao = fdot2f(__builtin_bit_cast(half2v, woP[j]), hpj, ao);
            }
            pbuf[par][wv][l] = make_float4(ai, af, ag, ao);
            BAR_LGKM();

            // phase 2: own partial (regs) + other 3 chunks (3x ds_read_b128)
            float4 r0 = pbuf[par][(wv + 1) & 3][l];
            float4 r1 = pbuf[par][(wv + 2) & 3][l];
            float4 r2 = pbuf[par][(wv + 3) & 3][l];
            float si = (ai + r0.x) + (r1.x + r2.x);
            float sf = (af + r0.y) + (r1.y + r2.y);
            float sg = (ag + r0.z) + (r1.z + r2.z);
            float so = (ao + r0.w) + (r1.w + r2.w);
            float ig = sigmoid_f(si);
            float fg = sigmoid_f(sf);
            float gg = tanh_f(sg);
            float og = sigmoid_f(so);
            c = fmaf(fg, c, ig * gg);
            h = og * tanh_f(c);
        }
        zc0 = zn0; zc1 = zn1;
    }

    // head: out = W2 @ relu(W1 @ relu(h_T)) + b2
    if (tid < HID) hfin[tid] = h;
    __syncthreads();
    if (tid < 32) {
        float s = 0.0f;
#pragma unroll
        for (int j = 0; j < HID; ++j) s += W1[tid * HID + j] * fmaxf(hfin[j], 0.0f);
        hbuf[tid] = fmaxf(s, 0.0f);
    }
    __syncthreads();
    if (tid < 3) {
        float s = b2[tid];
#pragma unroll
        for (int j = 0; j < 32; ++j) s += W2[tid * 32 + j] * hbuf[j];
        out[tid] = s;
    }
}

extern "C" void kernel_launch(void* const* d_in, const int* in_sizes, int n_in,
                              void* d_out, int out_size, void* d_ws, size_t ws_size,
                              hipStream_t stream) {
    const float* x   = (const float*)d_in[0];
    const float* Wih = (const float*)d_in[1];
    const float* Whh = (const float*)d_in[2];
    const float* bih = (const float*)d_in[3];
    const float* bhh = (const float*)d_in[4];
    const float* W1  = (const float*)d_in[5];
    const float* W2  = (const float*)d_in[6];
    const float* b2  = (const float*)d_in[7];
    float* out = (float*)d_out;
    float* xz2 = (float*)d_ws;   // T_STEPS * 256 floats = 64 MB (transposed layout)

    xz_kernel<<<T_STEPS / TS, 256, 0, stream>>>(x, Wih, bih, bhh, xz2);
    lstm_kernel<<<1, 256, 0, stream>>>(xz2, Whh, W1, W2, b2, out);
}